// Round 9
// baseline (2922.962 us; speedup 1.0000x reference)
//
#include <hip/hip_runtime.h>

// Problem constants (fixed by setup_inputs)
constexpr int B    = 64;     // batch_size
constexpr int NMAX = 768;    // max_num_nodes
constexpr int H    = 16;     // num_heads
constexpr int F    = 512;    // hidden dim
constexpr float NEG_INF = -1000000000.0f;

typedef float f32x4 __attribute__((ext_vector_type(4)));

// ---------------------------------------------------------------------------
// Kernel 1: per-graph starts & counts via binary search on sorted batch_ids.
// d_ws layout: [0..B) = starts, [B..2B) = counts
// ---------------------------------------------------------------------------
__global__ void k_starts(const int* __restrict__ batch_ids, int N,
                         int* __restrict__ starts_counts) {
    int b = threadIdx.x;
    if (b >= B) return;
    auto lb = [&](int v) {           // first index with batch_ids[i] >= v
        int lo = 0, hi = N;
        while (lo < hi) {
            int mid = (lo + hi) >> 1;
            if (batch_ids[mid] < v) lo = mid + 1; else hi = mid;
        }
        return lo;
    };
    int s = lb(b);
    int e = lb(b + 1);
    starts_counts[b]     = s;
    starts_counts[B + b] = e - s;
}

// ---------------------------------------------------------------------------
// Kernel 2: dense_x gather (one f32x4 per thread) + Dmask.
// ---------------------------------------------------------------------------
__global__ void k_dense(const f32x4* __restrict__ x4,
                        const int* __restrict__ sc,
                        f32x4* __restrict__ dense4,
                        float* __restrict__ dmask) {
    constexpr int F4 = F / 4;  // 128 f32x4 per row
    int idx = blockIdx.x * blockDim.x + threadIdx.x;   // < B*NMAX*F4
    int row = idx / F4;
    int j   = idx - row * F4;
    int b   = row / NMAX;
    int p   = row - b * NMAX;
    int cnt = sc[B + b];
    bool occ = (p < cnt);
    f32x4 v = (f32x4){0.f, 0.f, 0.f, 0.f};
    if (occ) {
        int src = sc[b] + p;
        v = x4[src * F4 + j];
    }
    dense4[idx] = v;
    if (j == 0) dmask[row] = occ ? 1.0f : 0.0f;
}

// ---------------------------------------------------------------------------
// Kernel 3: attn_mask writer (2.416 GB) — grid-cooperative contiguous sweep.
// CALIBRATION ROUND: launched TWICE (idempotent). The dur_us delta vs the
// round-7 baseline (2500 µs) directly measures this kernel's duration,
// which rocprof's top-5 has been hiding.
// ---------------------------------------------------------------------------
constexpr int K4       = NMAX / 4;                // 192 f32x4 per key row
constexpr int PER_B    = H * NMAX * K4;           // 2,359,296 f32x4 per graph
constexpr int MBLOCKS  = 4608;                    // grid size
constexpr int MTHREADS = MBLOCKS * 256;           // 1,179,648 = sweep stride
static_assert(MTHREADS % K4 == 0, "k4 invariance");
static_assert(PER_B == 2 * MTHREADS, "b = iter>>1");

__global__ __launch_bounds__(256) void k_mask(const int* __restrict__ counts,
                                              f32x4* __restrict__ out4) {
    __shared__ int cnt_s[B];
    if (threadIdx.x < B) cnt_s[threadIdx.x] = counts[threadIdx.x];
    __syncthreads();

    int idx0 = blockIdx.x * 256 + threadIdx.x;    // < MTHREADS
    int k4   = idx0 % K4;                         // invariant under +stride
    int k    = k4 * 4;

    f32x4* p = out4 + idx0;
    #pragma unroll 4
    for (int b = 0; b < B; ++b) {                 // uniform across threads
        int c = cnt_s[b];                         // LDS broadcast
        f32x4 v;
        v.x = (k + 0 < c) ? 0.0f : NEG_INF;
        v.y = (k + 1 < c) ? 0.0f : NEG_INF;
        v.z = (k + 2 < c) ? 0.0f : NEG_INF;
        v.w = (k + 3 < c) ? 0.0f : NEG_INF;
        *p = v;  p += MTHREADS;                   // contiguous grid sweep
        *p = v;  p += MTHREADS;
    }
}

// ---------------------------------------------------------------------------
extern "C" void kernel_launch(void* const* d_in, const int* in_sizes, int n_in,
                              void* d_out, int out_size, void* d_ws, size_t ws_size,
                              hipStream_t stream) {
    const float* x        = (const float*)d_in[0];
    const int* batch_ids  = (const int*)d_in[1];
    const int N           = in_sizes[1];                 // 32768

    int* sc = (int*)d_ws;                                // starts[B], counts[B]

    float* out = (float*)d_out;
    // Output layout: dense_x | Dmask | attn (flat, return order)
    float* dense = out;
    float* dmask = out + (size_t)B * NMAX * F;
    float* attn  = dmask + (size_t)B * NMAX;             // 16B-aligned offset

    // 1) starts/counts
    k_starts<<<1, 64, 0, stream>>>(batch_ids, N, sc);

    // 2) dense_x + Dmask
    {
        int total4 = B * NMAX * (F / 4);                 // 6,291,456
        int block  = 256;
        int grid   = (total4 + block - 1) / block;       // 24,576 blocks
        k_dense<<<grid, block, 0, stream>>>((const f32x4*)x, sc,
                                            (f32x4*)dense, dmask);
    }

    // 3) attn_mask — TWICE (calibration: delta vs round 7 == t(k_mask))
    k_mask<<<MBLOCKS, 256, 0, stream>>>(sc + B, (f32x4*)attn);
    k_mask<<<MBLOCKS, 256, 0, stream>>>(sc + B, (f32x4*)attn);
}

// Round 10
// 2499.247 us; speedup vs baseline: 1.1695x; 1.1695x over previous
//
#include <hip/hip_runtime.h>

// Problem constants (fixed by setup_inputs)
constexpr int B    = 64;     // batch_size
constexpr int NMAX = 768;    // max_num_nodes
constexpr int H    = 16;     // num_heads
constexpr int F    = 512;    // hidden dim
constexpr float NEG_INF = -1000000000.0f;

typedef float f32x4 __attribute__((ext_vector_type(4)));

// ---------------------------------------------------------------------------
// Roofline accounting (round-9 calibration, MI355X):
//   k_mask  = 423 µs measured (2.416 GB @ 5.71 TB/s = 93% of the 6.15 TB/s
//             the harness's own fillBufferAligned achieves on this buffer)
//   k_dense ≈ 30 µs (165 MB), k_starts ≈ 4 µs
//   dur_us ≈ 2500 = ours ~457 µs + fixed harness re-poison tax ~2045 µs.
// Output bytes (2.516 GB) are mandated by the reference signature; the
// kernel set is store-bandwidth-bound at the achievable ceiling.
// ---------------------------------------------------------------------------

// ---------------------------------------------------------------------------
// Kernel 1: per-graph starts & counts via binary search on sorted batch_ids.
// d_ws layout: [0..B) = starts, [B..2B) = counts
// ---------------------------------------------------------------------------
__global__ void k_starts(const int* __restrict__ batch_ids, int N,
                         int* __restrict__ starts_counts) {
    int b = threadIdx.x;
    if (b >= B) return;
    auto lb = [&](int v) {           // first index with batch_ids[i] >= v
        int lo = 0, hi = N;
        while (lo < hi) {
            int mid = (lo + hi) >> 1;
            if (batch_ids[mid] < v) lo = mid + 1; else hi = mid;
        }
        return lo;
    };
    int s = lb(b);
    int e = lb(b + 1);
    starts_counts[b]     = s;
    starts_counts[B + b] = e - s;
}

// ---------------------------------------------------------------------------
// Kernel 2: dense_x gather (one f32x4 per thread) + Dmask.
// dense_x[b,p,:] = (p < counts[b]) ? x[starts[b]+p, :] : 0
// Gather formulation: no zero-init, no scatter, fully coalesced.
// ---------------------------------------------------------------------------
__global__ void k_dense(const f32x4* __restrict__ x4,
                        const int* __restrict__ sc,
                        f32x4* __restrict__ dense4,
                        float* __restrict__ dmask) {
    constexpr int F4 = F / 4;  // 128 f32x4 per row
    int idx = blockIdx.x * blockDim.x + threadIdx.x;   // < B*NMAX*F4
    int row = idx / F4;
    int j   = idx - row * F4;
    int b   = row / NMAX;
    int p   = row - b * NMAX;
    int cnt = sc[B + b];
    bool occ = (p < cnt);
    f32x4 v = (f32x4){0.f, 0.f, 0.f, 0.f};
    if (occ) {
        int src = sc[b] + p;
        v = x4[src * F4 + j];
    }
    dense4[idx] = v;
    if (j == 0) dmask[row] = occ ? 1.0f : 0.0f;
}

// ---------------------------------------------------------------------------
// Kernel 3: attn_mask writer (2.416 GB) — grid-cooperative contiguous sweep.
// k4 = idx % 192 invariant across iterations; b uniform across all threads;
// counts[] in LDS; inner loop is pure global_store_dwordx4.
// Measured 423 µs = 5.71 TB/s (round-9 double-launch calibration).
// ---------------------------------------------------------------------------
constexpr int K4       = NMAX / 4;                // 192 f32x4 per key row
constexpr int PER_B    = H * NMAX * K4;           // 2,359,296 f32x4 per graph
constexpr int MBLOCKS  = 4608;                    // grid size
constexpr int MTHREADS = MBLOCKS * 256;           // 1,179,648 = sweep stride
static_assert(MTHREADS % K4 == 0, "k4 invariance");
static_assert(PER_B == 2 * MTHREADS, "b = iter>>1");

__global__ __launch_bounds__(256) void k_mask(const int* __restrict__ counts,
                                              f32x4* __restrict__ out4) {
    __shared__ int cnt_s[B];
    if (threadIdx.x < B) cnt_s[threadIdx.x] = counts[threadIdx.x];
    __syncthreads();

    int idx0 = blockIdx.x * 256 + threadIdx.x;    // < MTHREADS
    int k4   = idx0 % K4;                         // invariant under +stride
    int k    = k4 * 4;

    f32x4* p = out4 + idx0;
    #pragma unroll 4
    for (int b = 0; b < B; ++b) {                 // uniform across threads
        int c = cnt_s[b];                         // LDS broadcast
        f32x4 v;
        v.x = (k + 0 < c) ? 0.0f : NEG_INF;
        v.y = (k + 1 < c) ? 0.0f : NEG_INF;
        v.z = (k + 2 < c) ? 0.0f : NEG_INF;
        v.w = (k + 3 < c) ? 0.0f : NEG_INF;
        *p = v;  p += MTHREADS;                   // contiguous grid sweep
        *p = v;  p += MTHREADS;
    }
}

// ---------------------------------------------------------------------------
extern "C" void kernel_launch(void* const* d_in, const int* in_sizes, int n_in,
                              void* d_out, int out_size, void* d_ws, size_t ws_size,
                              hipStream_t stream) {
    const float* x        = (const float*)d_in[0];
    const int* batch_ids  = (const int*)d_in[1];
    const int N           = in_sizes[1];                 // 32768

    int* sc = (int*)d_ws;                                // starts[B], counts[B]

    float* out = (float*)d_out;
    // Output layout: dense_x | Dmask | attn (flat, return order)
    float* dense = out;
    float* dmask = out + (size_t)B * NMAX * F;
    float* attn  = dmask + (size_t)B * NMAX;             // 16B-aligned offset

    // 1) starts/counts
    k_starts<<<1, 64, 0, stream>>>(batch_ids, N, sc);

    // 2) dense_x + Dmask
    {
        int total4 = B * NMAX * (F / 4);                 // 6,291,456
        int block  = 256;
        int grid   = (total4 + block - 1) / block;       // 24,576 blocks
        k_dense<<<grid, block, 0, stream>>>((const f32x4*)x, sc,
                                            (f32x4*)dense, dmask);
    }

    // 3) attn_mask — single launch (calibration scaffold removed)
    k_mask<<<MBLOCKS, 256, 0, stream>>>(sc + B, (f32x4*)attn);
}